// Round 16
// baseline (58.543 us; speedup 1.0000x reference)
//
#include <hip/hip_runtime.h>
#include <hip/hip_bf16.h>
#include <math.h>

#define BB   8
#define CC   80
#define HH   128
#define WW   128
#define HWN  16384
#define KTOP 100
#define NSTRIP 8
#define SR   16
#define LR   (SR + 4)
#define SCAP 512
#define REG  100        // fixed per-strip region: strip lex-top-100 superset-suffices

typedef unsigned long long ull;

// FINAL (R16 == R11, the measured optimum of the session: 54.9us, absmax 0.0).
// Ladder: 713 (R1) -> 151.7 (R3) -> 65.9 (R4) -> 54.9 (R11).
// Refuted dead-ends, kept as design constraints:
//  - R6: 8-block shfl-chain tail = 170us (serial latency; distribute the reduce)
//  - R7/R8: runtime-indexed wv[12] -> scratch demotion (rule #20)
//  - R10->R11: 5120 blocks atomicAdd-ing 8 counters in one line across 8
//    non-coherent XCD L2s cost ~20us (G12) — fixed-region writes instead
//  - R12 (rolling-reg+shfl NMS), R13 (fused V+H), R14 (T14 pairing),
//    R15 (T1 XCD swizzle): all 57-60us, worse than this plain two-pass.

__device__ __forceinline__ float sigmoidf_(float x) {
    // bitwise-matched vs jax.nn.sigmoid (validated R1/R3/R4/R6-R15)
    if (x >= 0.0f) return 1.0f / (1.0f + expf(-x));
    float e = expf(x);
    return e / (1.0f + e);
}

// value desc, class asc, hw asc; unique per (map,hw). Ordering == reference
// two-stage top-k (superset-filter proof R2-R4, bitwise-validated through R15).
__device__ __forceinline__ ull makekey(float v, int cls, int hw) {
    return ((ull)__float_as_uint(v) << 21)
         | ((ull)(127 - cls) << 14)
         | (ull)(16383 - hw);
}

#define BITONIC_DESC(arr, N2, NTHR)                                         \
    for (int k_ = 2; k_ <= (N2); k_ <<= 1) {                                \
        for (int j_ = k_ >> 1; j_ > 0; j_ >>= 1) {                          \
            for (int i_ = threadIdx.x; i_ < (N2); i_ += (NTHR)) {           \
                const int ixj_ = i_ ^ j_;                                   \
                if (ixj_ > i_) {                                            \
                    ull a_ = (arr)[i_], b_ = (arr)[ixj_];                   \
                    if (((i_ & k_) == 0) ? (a_ < b_) : (a_ > b_)) {         \
                        (arr)[i_] = b_; (arr)[ixj_] = a_;                   \
                    }                                                       \
                }                                                           \
            }                                                               \
            __syncthreads();                                                \
        }                                                                   \
    }

// ---- Kernel A: two-pass 5x5 NMS per 16-row strip; fixed-region write ----
__global__ __launch_bounds__(256) void knms(const float* __restrict__ logits,
                                            ull* __restrict__ slab,
                                            int* __restrict__ scount) {
    __shared__ __align__(16) float s[LR][WW];    // 10 KB sigmoid tile (halo-clamped)
    __shared__ __align__(16) float vm[SR][WW];   // 8 KB vertical 5-max
    __shared__ ull cand[SCAP];                   // 4 KB
    __shared__ int cnt;

    const int tid   = threadIdx.x;
    const int map   = blockIdx.x >> 3;           // b*CC + c
    const int strip = blockIdx.x & 7;
    const int cls   = map % CC;
    const int R0    = strip * SR;
    const float* __restrict__ src = logits + (size_t)map * HWN;
    if (tid == 0) cnt = 0;

    // stage sigmoid tile, float4, halo rows clamped (== -inf pad for window max)
    for (int v = tid; v < LR * 32; v += 256) {
        const int lr = v >> 5, c4 = (v & 31) << 2;
        int gr = R0 - 2 + lr;
        gr = gr < 0 ? 0 : (gr > HH - 1 ? HH - 1 : gr);
        const float4 f = *reinterpret_cast<const float4*>(src + (size_t)gr * WW + c4);
        float4 o;
        o.x = sigmoidf_(f.x); o.y = sigmoidf_(f.y);
        o.z = sigmoidf_(f.z); o.w = sigmoidf_(f.w);
        *reinterpret_cast<float4*>(&s[lr][c4]) = o;
    }
    __syncthreads();

    // vertical 5-max per column
    for (int i = tid; i < SR * WW; i += 256) {
        const int r = i >> 7, c = i & 127;
        float m = fmaxf(fmaxf(s[r][c], s[r + 1][c]), fmaxf(s[r + 2][c], s[r + 3][c]));
        vm[r][c] = fmaxf(m, s[r + 4][c]);
    }
    __syncthreads();

    // horizontal 5-max + keep + block compact
    for (int i = tid; i < SR * WW; i += 256) {
        const int r = i >> 7, c = i & 127;
        const int cm2 = c - 2 < 0 ? 0 : c - 2;
        const int cm1 = c - 1 < 0 ? 0 : c - 1;
        const int cp1 = c + 1 > 127 ? 127 : c + 1;
        const int cp2 = c + 2 > 127 ? 127 : c + 2;
        float m = fmaxf(fmaxf(vm[r][cm2], vm[r][cm1]), fmaxf(vm[r][c], vm[r][cp1]));
        m = fmaxf(m, vm[r][cp2]);
        const float v = s[r + 2][c];
        if (v == m) {   // exact reference keep: sigma == 5x5 sigma-max
            const int slot = atomicAdd(&cnt, 1);
            if (slot < SCAP) cand[slot] = makekey(v, cls, ((R0 + r) << 7) | c);
        }
    }
    __syncthreads();

    const int n = cnt < SCAP ? cnt : SCAP;
    ull* __restrict__ dst = slab + (size_t)blockIdx.x * REG;
    if (n <= REG) {
        // fast path (n~82): unsorted write + count — no global atomics
        for (int i = tid; i < n; i += 256) dst[i] = cand[i];
        if (tid == 0) scount[blockIdx.x] = n;
    } else {
        // rare path: exact lex-top-100 via in-LDS bitonic
        int n2 = 128;
        while (n2 < n) n2 <<= 1;
        for (int i = tid; i < n2; i += 256) if (i >= n) cand[i] = 0ULL;
        __syncthreads();
        BITONIC_DESC(cand, n2, 256);
        for (int i = tid; i < REG; i += 256) dst[i] = cand[i];
        if (tid == 0) scount[blockIdx.x] = REG;
    }
}

// ---- in-register wave bitonic helpers (64 lanes) ----
__device__ __forceinline__ ull sort64_desc(ull v, int lane) {
    for (int k = 2; k <= 64; k <<= 1) {
        for (int j = k >> 1; j >= 1; j >>= 1) {
            const ull p = __shfl_xor(v, j, 64);
            const bool km = (((lane & k) == 0) != ((lane & j) != 0));
            v = (km == (p > v)) ? p : v;
        }
    }
    return v;
}

__device__ __forceinline__ void bmerge128(ull& a0, ull& a1, int lane) {
    const ull t0 = a0 > a1 ? a0 : a1;
    a1 = a0 > a1 ? a1 : a0;
    a0 = t0;
    for (int j = 32; j >= 1; j >>= 1) {
        const ull p0 = __shfl_xor(a0, j, 64);
        const ull p1 = __shfl_xor(a1, j, 64);
        const bool km = ((lane & j) == 0);
        a0 = (km == (p0 > a0)) ? p0 : a0;
        a1 = (km == (p1 > a1)) ? p1 : a1;
    }
}

// ---- Kernel B: per map (640 blocks): 8 waves sort one strip each, merge -> top-128 ----
__global__ __launch_bounds__(512) void kred(const ull* __restrict__ slab,
                                            const int* __restrict__ scount,
                                            ull* __restrict__ lists) {
    __shared__ ull ls[8][128];
    const int tid = threadIdx.x, w = tid >> 6, lane = tid & 63;
    const int map = blockIdx.x;
    const int sg = map * NSTRIP + w;             // global strip id for this wave

    const int n = scount[sg];
    const ull* __restrict__ base = slab + (size_t)sg * REG;

    ull a0 = 0ULL, a1 = 0ULL;
#pragma unroll
    for (int c = 0; c < 2; ++c) {
        const int idx = c * 64 + lane;
        ull v = (idx < n) ? base[idx] : 0ULL;
        v = sort64_desc(v, lane);
        const ull rv = __shfl(v, 63 - lane, 64);
        a1 = a1 > rv ? a1 : rv;
        bmerge128(a0, a1, lane);
    }
    ls[w][lane] = a0;
    ls[w][64 + lane] = a1;

    for (int half = 4; half >= 1; half >>= 1) {
        __syncthreads();
        ull z0 = 0ULL, z1 = 0ULL;
        const bool act = (w < half);
        if (act) {
            const ull l0 = ls[2 * w][lane];
            const ull l1 = ls[2 * w][64 + lane];
            const ull r1r = ls[2 * w + 1][127 - lane];
            const ull r0r = ls[2 * w + 1][63 - lane];
            z0 = l0 > r1r ? l0 : r1r;
            z1 = l1 > r0r ? l1 : r0r;
            bmerge128(z0, z1, lane);
        }
        __syncthreads();
        if (act) { ls[w][lane] = z0; ls[w][64 + lane] = z1; }
    }
    __syncthreads();
    if (tid < 128)
        lists[(size_t)map * 128 + tid] = ls[0][tid];
}

// ---- Kernel C: per batch: 16 waves reg-merge 5 map-lists each, tree, decode ----
__global__ __launch_bounds__(1024) void kfin(const ull* __restrict__ lists,
                                             const float* __restrict__ txty,
                                             const float* __restrict__ twth,
                                             float* __restrict__ out) {
    __shared__ ull ls[16][128];                  // 16 KB
    const int tid = threadIdx.x, b = blockIdx.x;
    const int w = tid >> 6, lane = tid & 63;
    const ull* __restrict__ L = lists + (size_t)b * CC * 128;

    const ull* __restrict__ l0 = L + (size_t)(5 * w) * 128;
    ull a0 = l0[lane], a1 = l0[64 + lane];
#pragma unroll
    for (int k = 1; k < 5; ++k) {
        const ull* __restrict__ lk = L + (size_t)(5 * w + k) * 128;
        const ull r0 = lk[127 - lane];
        const ull r1 = lk[63 - lane];
        a0 = a0 > r0 ? a0 : r0;
        a1 = a1 > r1 ? a1 : r1;
        bmerge128(a0, a1, lane);
    }
    ls[w][lane] = a0;
    ls[w][64 + lane] = a1;

    for (int half = 8; half >= 1; half >>= 1) {
        __syncthreads();
        ull z0 = 0ULL, z1 = 0ULL;
        const bool act = (w < half);
        if (act) {
            const ull t0 = ls[2 * w][lane];
            const ull t1 = ls[2 * w][64 + lane];
            const ull r1r = ls[2 * w + 1][127 - lane];
            const ull r0r = ls[2 * w + 1][63 - lane];
            z0 = t0 > r1r ? t0 : r1r;
            z1 = t1 > r0r ? t1 : r0r;
            bmerge128(z0, z1, lane);
        }
        __syncthreads();
        if (act) { ls[w][lane] = z0; ls[w][64 + lane] = z1; }
    }
    __syncthreads();

    if (tid < KTOP) {
        const ull key = ls[0][tid];
        const int hw  = 16383 - (int)(key & 0x3FFFULL);
        const int cls = 127 - (int)((key >> 14) & 0x7FULL);
        const float sc = __uint_as_float((unsigned int)(key >> 21));

        // out layout (float32): score[0..800) | bbox[800..4000) | inds[4000..4800) | clses[4800..5600)
        out[b * KTOP + tid]        = sc;
        out[4000 + b * KTOP + tid] = (float)hw;
        out[4800 + b * KTOP + tid] = (float)cls;

        const int xx = hw & 127, yy = hw >> 7;
        const float* __restrict__ t = txty + (size_t)b * 2 * HWN;
        const float* __restrict__ u = twth + (size_t)b * 2 * HWN;
        const float tx = t[hw], ty = t[HWN + hw];
        const float tw = u[hw], th = u[HWN + hw];

        const float cx = (sigmoidf_(tx) + (float)xx) * 4.0f;
        const float cy = (sigmoidf_(ty) + (float)yy) * 4.0f;
        const float bw = expf(tw) * 4.0f;
        const float bh = expf(th) * 4.0f;

        const float inv = 1.0f / 512.0f;
        float x1 = (cx - bw * 0.5f) * inv;
        float y1 = (cy - bh * 0.5f) * inv;
        float x2 = (cx + bw * 0.5f) * inv;
        float y2 = (cy + bh * 0.5f) * inv;
        x1 = fminf(fmaxf(x1, 0.0f), 1.0f);
        y1 = fminf(fmaxf(y1, 0.0f), 1.0f);
        x2 = fminf(fmaxf(x2, 0.0f), 1.0f);
        y2 = fminf(fmaxf(y2, 0.0f), 1.0f);

        float* bb = out + 800 + (size_t)(b * KTOP + tid) * 4;
        bb[0] = x1; bb[1] = y1; bb[2] = x2; bb[3] = y2;
    }
}

extern "C" void kernel_launch(void* const* d_in, const int* in_sizes, int n_in,
                              void* d_out, int out_size, void* d_ws, size_t ws_size,
                              hipStream_t stream) {
    const float* cls_logits = (const float*)d_in[0];
    const float* txty       = (const float*)d_in[1];
    const float* twth       = (const float*)d_in[2];
    float* out = (float*)d_out;

    // ws layout (bytes):
    //   slab:   5120 strips * 100 * 8 = 4,096,000
    //   scount: 5120 * 4             =    20,480   @ 4,096,000
    //   lists:  640 * 128 * 8        =   655,360   @ 4,116,480
    // total 4,771,840 — every byte read is written first (no memset needed)
    ull* slab   = (ull*)d_ws;
    int* scount = (int*)((char*)d_ws + 4096000);
    ull* lists  = (ull*)((char*)d_ws + 4116480);

    knms<<<BB * CC * NSTRIP, 256, 0, stream>>>(cls_logits, slab, scount);
    kred<<<BB * CC,          512, 0, stream>>>(slab, scount, lists);
    kfin<<<BB,              1024, 0, stream>>>(lists, txty, twth, out);
}